// Round 12
// baseline (460.071 us; speedup 1.0000x reference)
//
#include <hip/hip_runtime.h>
#include <hip/hip_bf16.h>

#define NN 528
#define NP (NN*NN)
#define IMG 512
#define IMGP (IMG*IMG)
#define PAD 8
#define KH 17
#define KT (KH*KH)
#define NF 24
#define RK 5
#define RKT (RK*RK)
#define ND 4
// per-channel border pixel counts
#define TOPB (17*NN)
#define ROWB (2*TOPB)
#define SIDEB (494*34)
#define BORD (ROWB + SIDEB)     // 34748
#define AST 34                  // padded A stride: even k2 is 16B-aligned for float4 reads
#define NQ 265                  // Hermitian slow-row count
#define TPB 320                 // FFT kernel block size: 528/320 -> 2 rounds (no 3rd-round tail)

static __device__ __forceinline__ float ldx(const void* p, long i, int bf) {
    if (bf) return __bfloat162float(((const __hip_bfloat16*)p)[i]);
    return ((const float*)p)[i];
}

// mirror-of-circular map: padded-domain offset m in [-16, 528) -> source index in [0,512)
static __device__ __forceinline__ int gmap(int m) {
    if (m < -8)  return 495 - m;   // -16..-9  -> 511..504
    if (m < 0)   return -m - 1;    // -8..-1   -> 7..0
    if (m < 512) return m;
    if (m < 520) return 1023 - m;  // 512..519 -> 511..504
    return 527 - m;                // 520..527 -> 7..0
}

// ---- 2-wide FFT stage bodies; compile-time sign S folds into FMA modifiers ----
// stage 1: task = k2*8 + n1h; outputs A[2*n1h][k2], A[2*n1h+1][k2].
// Twiddle w_n = T33[k2]^n generated in-register (1 LDS read/task).
// Epilogue twiddles read from GLOBAL twN (L2-resident; 2 reads per ~1000-cyc task).
template<int S>
static __device__ __forceinline__ void s1_pair(const float2* __restrict__ X,
                                               float2* __restrict__ A,
                                               const float2* __restrict__ twNg,
                                               const float2* __restrict__ T33,
                                               int task) {
    int k2 = task >> 3, n1h = task & 7, n1 = n1h << 1;
    const float4* Xv = (const float4*)X;
    float2 wst = T33[k2];
    float wr = 1.f, wi = 0.f;
    float a0r = 0.f, a0i = 0.f, a1r = 0.f, a1i = 0.f;
    for (int n2 = 0; n2 < 33; ++n2) {
        float4 xv = Xv[n1h + 8*n2];
        float ur = wr, ui = (S > 0) ? wi : -wi;
        a0r += xv.x*ur - xv.y*ui; a0i += xv.x*ui + xv.y*ur;
        a1r += xv.z*ur - xv.w*ui; a1i += xv.z*ui + xv.w*ur;
        float nwr = wr*wst.x - wi*wst.y;
        wi = wr*wst.y + wi*wst.x;
        wr = nwr;
    }
    float2 t0 = twNg[n1*k2], t1 = twNg[(n1+1)*k2];
    float t0r = t0.x, t0i = (S > 0) ? t0.y : -t0.y;
    float t1r = t1.x, t1i = (S > 0) ? t1.y : -t1.y;
    A[n1*AST + k2]     = make_float2(a0r*t0r - a0i*t0i, a0r*t0i + a0i*t0r);
    A[(n1+1)*AST + k2] = make_float2(a1r*t1r - a1i*t1i, a1r*t1i + a1i*t1r);
}

// stage 2: task = k1*17 + kp. kp<16 -> pair (2kp,2kp+1), kp=16 -> solo k2=32.
// Twiddle w_n = T16[k1]^n in-register (1 LDS read/task).
template<int S>
static __device__ __forceinline__ void s2_pair(const float2* __restrict__ A,
                                               const float2* __restrict__ T16,
                                               int task,
                                               int* o0, float2* y0, int* o1, float2* y1) {
    int k1 = task / 17, kp = task - 17*k1;
    float2 wst = T16[k1];
    float wr = 1.f, wi = 0.f;
    if (kp < 16) {
        int k2 = kp << 1;
        const float4* Av = (const float4*)A;
        float a0r = 0.f, a0i = 0.f, a1r = 0.f, a1i = 0.f;
        for (int n1 = 0; n1 < 16; ++n1) {
            float4 av = Av[(n1*AST + k2) >> 1];
            float ur = wr, ui = (S > 0) ? wi : -wi;
            a0r += av.x*ur - av.y*ui; a0i += av.x*ui + av.y*ur;
            a1r += av.z*ur - av.w*ui; a1i += av.z*ui + av.w*ur;
            float nwr = wr*wst.x - wi*wst.y;
            wi = wr*wst.y + wi*wst.x;
            wr = nwr;
        }
        *o0 = k1*33 + k2;     *y0 = make_float2(a0r, a0i);
        *o1 = k1*33 + k2 + 1; *y1 = make_float2(a1r, a1i);
    } else {
        float a0r = 0.f, a0i = 0.f;
        for (int n1 = 0; n1 < 16; ++n1) {
            float2 av = A[n1*AST + 32];
            float ur = wr, ui = (S > 0) ? wi : -wi;
            a0r += av.x*ur - av.y*ui; a0i += av.x*ui + av.y*ur;
            float nwr = wr*wst.x - wi*wst.y;
            wi = wr*wst.y + wi*wst.x;
            wr = nwr;
        }
        *o0 = k1*33 + 32; *y0 = make_float2(a0r, a0i);
        *o1 = -1;
    }
}

__global__ void detect_k(const void* pimg, int nimg, const void* pbk, int nbk,
                         const void* pwcw, int nwcw, const void* pws, int nws,
                         const float* c4a, const float* c4b,
                         int* __restrict__ flags,
                         float* __restrict__ alpha_ws, float* __restrict__ wgt_ws) {
    int t = threadIdx.x;
    const void* ps[4] = {pimg, pbk, pwcw, pws};
    int ns[4] = {nimg, nbk, nwcw, nws};
    if (t < 4) {
        const unsigned short* q = (const unsigned short*)ps[t];
        int n = ns[t];
        int K = n < 512 ? n : 512;
        int cnt = 0, pass = 0;
        for (int i = 0; i < K; i += 2) {
            int e = (q[i] >> 7) & 0xFF;
            pass += (e >= 100 && e <= 140);
            cnt++;
        }
        flags[t] = (pass * 10 >= cnt * 8) ? 1 : 0;
    }
    if (t == 7) {
        const float* A = (c4a[0] < 0.f) ? c4a : c4b;
        const float* W = (c4a[0] < 0.f) ? c4b : c4a;
        for (int i = 0; i < ND; ++i) { alpha_ws[i] = A[i]; wgt_ws[i] = W[i]; }
    }
}

__global__ void twinit_k(float2* __restrict__ twN) {
    int i = blockIdx.x * blockDim.x + threadIdx.x;
    if (i < NN) {
        double th = -6.283185307179586476925287 * (double)i / (double)NN;
        twN[i] = make_float2((float)cos(th), (float)sin(th));
    }
}

__global__ void wnorm_k(const void* __restrict__ wcw, const void* __restrict__ wscale,
                        const int* __restrict__ flags, float* __restrict__ wout) {
    int f = threadIdx.x;
    if (f >= NF) return;
    int bfw = flags[2], bfs = flags[3];
    float v[RKT];
    float mean = 0.f;
    for (int i = 0; i < RKT; ++i) { v[i] = ldx(wcw, f*RKT+i, bfw); mean += v[i]; }
    mean *= (1.f/(float)RKT);
    float ss = 0.f;
    for (int i = 0; i < RKT; ++i) { v[i] -= mean; ss += v[i]*v[i]; }
    float sc = ldx(wscale, f, bfs) / sqrtf(ss);
    for (int i = 0; i < RKT; ++i) wout[f*RKT+i] = v[i]*sc;
}

__global__ void prep_k(const void* __restrict__ blurKernel, const int* __restrict__ flags,
                       float* __restrict__ psf_all, float* __restrict__ A0_all,
                       float* __restrict__ A1_all) {
    int b = blockIdx.x, t = threadIdx.x;
    int bf = flags[1];
    __shared__ float psf[KT];
    __shared__ float q0[KH], q1[KH], ac0[KH], ac1[KH];
    for (int i = t; i < KT; i += 64) {
        float v = ldx(blurKernel, b*KT + i, bf);
        psf[i] = v;
        psf_all[b*KT + i] = v;
    }
    __syncthreads();
    if (t < KH) {
        float s0 = 0.f, s1 = 0.f;
        for (int k = 0; k < KH; ++k) { s0 += psf[t*KH + k]; s1 += psf[k*KH + t]; }
        q0[t] = s0; q1[t] = s1;
    }
    __syncthreads();
    if (t < KH) {
        float a0 = 0.f, a1 = 0.f;
        for (int m = 0; m + t < KH; ++m) { a0 += q0[m]*q0[m+t]; a1 += q1[m]*q1[m+t]; }
        ac0[t] = a0; ac1[t] = a1;
    }
    __syncthreads();
    for (int r = t; r < NN; r += 64) {
        int lag = min(r, (NN-1) - r);
        float b0 = (lag <= KH-1) ? ac0[lag]/ac0[0] : 0.f;
        float b1 = (lag <= KH-1) ? ac1[lag]/ac1[0] : 0.f;
        A0_all[b*NN + r] = 1.f - b0;
        A1_all[b*NN + r] = 1.f - b1;
    }
}

// Greg in transposed frequency layout: p = kc*NN + kr (verified R6)
__global__ void greg_k(const float* __restrict__ w, const float2* __restrict__ twN,
                       float* __restrict__ Greg) {
    int p = blockIdx.x * blockDim.x + threadIdx.x;
    if (p >= NP) return;
    int u = p % NN, v = p / NN;
    float2 rp[RK], cp[RK];
    for (int j = 0; j < RK; ++j) {
        int m = (u * (j - RK/2)) % NN; if (m < 0) m += NN;
        rp[j] = twN[m];
    }
    for (int k = 0; k < RK; ++k) {
        int m = (v * (k - RK/2)) % NN; if (m < 0) m += NN;
        cp[k] = twN[m];
    }
    float pr[RKT], pi[RKT];
    for (int j = 0; j < RK; ++j)
        for (int k = 0; k < RK; ++k) {
            pr[j*RK+k] = rp[j].x*cp[k].x - rp[j].y*cp[k].y;
            pi[j*RK+k] = rp[j].x*cp[k].y + rp[j].y*cp[k].x;
        }
    float acc = 0.f;
    for (int f = 0; f < NF; ++f) {
        float gr = 0.f, gi = 0.f;
        for (int i = 0; i < RKT; ++i) {
            float wv = w[f*RKT + i];
            gr += wv * pr[i];
            gi += wv * pi[i];
        }
        acc += gr*gr + gi*gi;
    }
    Greg[p] = acc;
}

// LDS-tiled border edgetaper (R1-verified).
__global__ __launch_bounds__(256)
void border2_k(const void* __restrict__ image, const int* __restrict__ flags,
               const float* __restrict__ psf_all,
               const float* __restrict__ A0_all, const float* __restrict__ A1_all,
               float* __restrict__ borderV) {
    __shared__ float4 S4[1440];           // 23040 B; tb uses 20x288 floats, side 42x84
    float* S = (float*)S4;
    int bp = blockIdx.y;                  // plane 0..23
    int b = bp / 3;
    long ofs = (long)bp * IMGP;
    int bf = flags[0];
    int t = threadIdx.x;
    const float* pw = psf_all + b*KT;
    int bx = blockIdx.x;

    if (bx < 20) {
        int q = bx >> 1, h = bx & 1;
        int r0;
        if (q < 4) r0 = 4*q;
        else if (q == 4) r0 = 13;
        else if (q < 9) r0 = 511 + 4*(q-5);
        else r0 = 524;
        int X0 = h * 264;
        for (int idx = t; idx < 20*288; idx += 256) {
            int i = idx / 288, xi = idx - i*288;
            int x = X0 + xi;
            float v = 0.f;
            if (x < 544) {
                int sr = gmap(r0 - 16 + i);
                int sc = gmap(x - 16);
                v = ldx(image, ofs + (long)sr*IMG + sc, bf);
            }
            S[idx] = v;
        }
        __syncthreads();
        for (int g = t; g < 264; g += 256) {
            int rx = g / 66, cl = g - rx*66;
            int c0 = X0 + 4*cl;
            int x0 = 4*cl;
            float acc0 = 0.f, acc1 = 0.f, acc2 = 0.f, acc3 = 0.f;
            for (int j = 0; j < KH; ++j) {
                const float4* SjV = (const float4*)(S + (16 + rx - j)*288 + x0);
                float xv[20];
                #pragma unroll
                for (int qv = 0; qv < 5; ++qv) {
                    float4 tv = SjV[qv];
                    xv[4*qv+0] = tv.x; xv[4*qv+1] = tv.y;
                    xv[4*qv+2] = tv.z; xv[4*qv+3] = tv.w;
                }
                const float* wj = pw + j*KH;
                #pragma unroll
                for (int qq = 0; qq < 20; ++qq) {
                    {int k = 0 + 16 - qq; if (k >= 0 && k < KH) acc0 += wj[k]*xv[qq];}
                    {int k = 1 + 16 - qq; if (k >= 0 && k < KH) acc1 += wj[k]*xv[qq];}
                    {int k = 2 + 16 - qq; if (k >= 0 && k < KH) acc2 += wj[k]*xv[qq];}
                    {int k = 3 + 16 - qq; if (k >= 0 && k < KH) acc3 += wj[k]*xv[qq];}
                }
            }
            int r = r0 + rx;
            float a0v = A0_all[b*NN + r];
            int ibase = (r < 17) ? r*NN : TOPB + (r-511)*NN;
            float accs[4] = {acc0, acc1, acc2, acc3};
            #pragma unroll
            for (int d = 0; d < 4; ++d) {
                int c = c0 + d;
                float xo = S[(8 + rx)*288 + (x0 + 8 + d)];
                float al = a0v * A1_all[b*NN + c];
                borderV[(size_t)bp*BORD + ibase + c] = al*xo + (1.f - al)*accs[d];
            }
        }
    } else {
        int chunk = bx - 20;
        int r0 = 17 + 26*chunk;
        for (int idx = t; idx < 42*84; idx += 256) {
            int i = idx / 84, x = idx - i*84;
            float v = 0.f;
            int m = -1000;
            if (x < 33) m = x - 16;
            else if (x >= 48 && x < 81) m = x - 48 + 495;
            if (m != -1000) {
                int sr = gmap(r0 - 16 + i);
                int sc = gmap(m);
                v = ldx(image, ofs + (long)sr*IMG + sc, bf);
            }
            S[idx] = v;
        }
        __syncthreads();
        int g = t;
        if (g < 208) {
            int ry = g >> 3, s = g & 7;
            int c0 = (s < 4) ? 4*s : 511 + 4*(s-4);
            int sz = ((s & 3) == 3) ? 5 : 4;
            int x0 = (s < 4) ? 4*s : 48 + 4*(s-4);
            float acc0=0.f, acc1=0.f, acc2=0.f, acc3=0.f, acc4=0.f;
            for (int j = 0; j < KH; ++j) {
                const float4* SjV = (const float4*)(S + (16 + ry - j)*84 + x0);
                float xv[24];
                #pragma unroll
                for (int qv = 0; qv < 6; ++qv) {
                    float4 tv = SjV[qv];
                    xv[4*qv+0] = tv.x; xv[4*qv+1] = tv.y;
                    xv[4*qv+2] = tv.z; xv[4*qv+3] = tv.w;
                }
                const float* wj = pw + j*KH;
                #pragma unroll
                for (int qq = 0; qq < 21; ++qq) {
                    {int k = 0 + 16 - qq; if (k >= 0 && k < KH) acc0 += wj[k]*xv[qq];}
                    {int k = 1 + 16 - qq; if (k >= 0 && k < KH) acc1 += wj[k]*xv[qq];}
                    {int k = 2 + 16 - qq; if (k >= 0 && k < KH) acc2 += wj[k]*xv[qq];}
                    {int k = 3 + 16 - qq; if (k >= 0 && k < KH) acc3 += wj[k]*xv[qq];}
                    {int k = 4 + 16 - qq; if (k >= 0 && k < KH) acc4 += wj[k]*xv[qq];}
                }
            }
            int r = r0 + ry;
            float a0v = A0_all[b*NN + r];
            int cc0 = (s < 4) ? c0 : c0 - 494;
            size_t ib = (size_t)bp*BORD + ROWB + (size_t)(r-17)*34 + cc0;
            float accs[5] = {acc0, acc1, acc2, acc3, acc4};
            #pragma unroll
            for (int d = 0; d < 5; ++d) {
                if (d < sz) {
                    int c = c0 + d;
                    float xo = S[(8 + ry)*84 + (x0 + 8 + d)];
                    float al = a0v * A1_all[b*NN + c];
                    borderV[ib + d] = al*xo + (1.f - al)*accs[d];
                }
            }
        }
    }
}

// column-sum factor S(b, v, j) = sum_k psf[b][j][k] * tw[v*(k-8)]  (u-independent part of K)
__global__ void kv_k(const float* __restrict__ psf_all, const float2* __restrict__ twN,
                     float2* __restrict__ Sv) {
    int idx = blockIdx.x * blockDim.x + threadIdx.x;
    if (idx >= 8*NN*KH) return;
    int j = idx % KH;
    int rest = idx / KH;
    int v = rest % NN, b = rest / NN;
    int m = (520 * v) % NN;   // (-8v) mod 528
    float sr = 0.f, si = 0.f;
    const float* ps = psf_all + b*KT + j*KH;
    for (int k = 0; k < KH; ++k) {
        float2 cp = twN[m];
        m += v; if (m >= NN) m -= NN;
        sr += ps[k] * cp.x;
        si += ps[k] * cp.y;
    }
    Sv[idx] = make_float2(sr, si);
}

// Precomputed Wiener filter field: Wf[((pair*NQ + q)*NN) + k] = (W0r, W0i, W1r, W1i).
__global__ __launch_bounds__(256)
void wfilt_k(const float2* __restrict__ Sv, const float* __restrict__ Greg,
             const float2* __restrict__ twN,
             const float* __restrict__ alpha4, const float* __restrict__ wgt4,
             float4* __restrict__ Wf) {
    int idx = blockIdx.x * blockDim.x + threadIdx.x;
    if (idx >= 4*NQ*NN) return;
    int k = idx % NN;
    int rest = idx / NN;
    int q = rest % NQ, pr = rest / NQ;
    int b0p = 2*pr;
    const float2* S0 = Sv + ((size_t)b0p*NN + q)*KH;
    const float2* S1 = Sv + ((size_t)(b0p+1)*NN + q)*KH;
    int mu0 = (520 * k) % NN;
    float2 rp = twN[mu0];
    float2 rst = twN[k];
    float K0r = 0.f, K0i = 0.f, K1r = 0.f, K1i = 0.f;
    for (int j = 0; j < KH; ++j) {
        float2 s0 = S0[j], s1 = S1[j];
        K0r += rp.x*s0.x - rp.y*s0.y;  K0i += rp.x*s0.y + rp.y*s0.x;
        K1r += rp.x*s1.x - rp.y*s1.y;  K1i += rp.x*s1.y + rp.y*s1.x;
        float nrp = rp.x*rst.x - rp.y*rst.y;
        rp.y = rp.x*rst.y + rp.y*rst.x;
        rp.x = nrp;
    }
    float gg = Greg[(size_t)q*NN + k];
    float K20 = K0r*K0r + K0i*K0i;
    float K21 = K1r*K1r + K1i*K1i;
    float s0a = 0.f, s1a = 0.f;
    #pragma unroll
    for (int d = 0; d < ND; ++d) {
        float a = __expf(alpha4[d]);
        float wd = wgt4[d];
        s0a += wd * __builtin_amdgcn_rcpf(fmaxf(K20 + a*gg, 1e-30f));
        s1a += wd * __builtin_amdgcn_rcpf(fmaxf(K21 + a*gg, 1e-30f));
    }
    s0a *= (1.f/(float)NP);
    s1a *= (1.f/(float)NP);
    Wf[idx] = make_float4(K0r*s0a, -K0i*s0a, K1r*s1a, -K1i*s1a);
}

// fused pad + forward row FFT, 2 rows per 320-thread block, all 12 packed planes
__global__ __launch_bounds__(TPB)
void fftrow_k(const void* __restrict__ image, const int* __restrict__ flags,
              const float* __restrict__ borderV, const float2* __restrict__ twN,
              float2* __restrict__ buf) {
    __shared__ __align__(16) float2 X[2][NN];
    __shared__ __align__(16) float2 A[2][16*AST];
    __shared__ float2 T33[33];
    __shared__ float2 T16[16];
    int t = threadIdx.x;
    int bid = blockIdx.x;               // 12 * 264
    int q = bid / 264;
    int r0 = (bid - q*264) << 1;
    int pair = q / 3, ch = q - 3*pair;
    int b0p = 2*pair;
    int bf = flags[0];
    if (t < 33) T33[t] = twN[t*16];
    else if (t >= 64 && t < 80) T16[t-64] = twN[(t-64)*33];
    for (int i = t; i < 2*NN; i += TPB) {
        int l = i / NN, c = i - l*NN;
        int r = r0 + l;
        float x0, x1;
        bool isb = (r < 17) | (r >= 511) | (c < 17) | (c >= 511);
        if (isb) {
            int i2;
            if (r < 17) i2 = r*NN + c;
            else if (r >= 511) i2 = TOPB + (r-511)*NN + c;
            else { int cc = (c < 17) ? c : c - 494; i2 = ROWB + (r-17)*34 + cc; }
            x0 = borderV[(size_t)(b0p*3 + ch)*BORD + i2];
            x1 = borderV[(size_t)((b0p+1)*3 + ch)*BORD + i2];
        } else {
            long ofs0 = ((long)b0p*3 + ch) * IMGP + (long)(r - PAD)*IMG + (c - PAD);
            x0 = ldx(image, ofs0, bf);
            x1 = ldx(image, ofs0 + 3L*IMGP, bf);
        }
        X[l][c] = make_float2(x0, x1);
    }
    __syncthreads();
    for (int i = t; i < 2*264; i += TPB) {
        int l = i / 264, task = i - 264*l;
        s1_pair<1>(X[l], A[l], twN, T33, task);
    }
    __syncthreads();
    for (int i = t; i < 2*272; i += TPB) {
        int l = i / 272, task = i - 272*l;
        int o0, o1; float2 y0, y1;
        s2_pair<1>(A[l], T16, task, &o0, &y0, &o1, &y1);
        float2* dst = buf + (size_t)q*NP + (size_t)(r0 + l)*NN;
        dst[o0] = y0;
        if (o1 >= 0) dst[o1] = y1;
    }
}

// in-place square transpose: tile-pair swap, 561 upper-tri tiles per plane (z = 12 planes)
__global__ void transpose_ip_k(float2* __restrict__ buf) {
    int tnum = blockIdx.x;
    int ti = 0, rem = tnum;
    while (rem >= 33 - ti) { rem -= 33 - ti; ti++; }
    int tj = ti + rem;
    float2* pl = buf + (size_t)blockIdx.z * NP;
    __shared__ float2 ta[16][17], tb[16][17];
    int tx = threadIdx.x, ty = threadIdx.y;
    int ra = ti*16 + ty, ca = tj*16 + tx;
    int rb = tj*16 + ty, cb = ti*16 + tx;
    ta[ty][tx] = pl[(size_t)ra*NN + ca];
    tb[ty][tx] = pl[(size_t)rb*NN + cb];
    __syncthreads();
    pl[(size_t)ra*NN + ca] = tb[tx][ty];
    pl[(size_t)rb*NN + cb] = ta[tx][ty];
}

// Fused cols-fwd + Wiener + cols-inv on TRANSPOSED buffer; W loaded from precomputed field.
__global__ __launch_bounds__(TPB)
void rowpipe_k(float2* __restrict__ buf, const float4* __restrict__ Wf,
               const float2* __restrict__ twN) {
    __shared__ __align__(16) float2 X[2][NN];
    __shared__ __align__(16) float2 A[2][16*AST];
    __shared__ float2 T33[33];
    __shared__ float2 T16[16];
    int t = threadIdx.x;
    int q = blockIdx.x;                 // 0..264
    int plane = blockIdx.y;             // 0..11
    int pr = plane / 3;
    int qm = (NN - q) % NN;
    int nrow = (qm == q) ? 1 : 2;
    float2* pl = buf + (size_t)plane * NP;
    if (t < 33) T33[t] = twN[t*16];
    else if (t >= 64 && t < 80) T16[t-64] = twN[(t-64)*33];
    // load rows (coalesced)
    for (int i = t; i < nrow*NN; i += TPB) {
        int l = i / NN, o = i - l*NN;
        X[l][o] = pl[(size_t)(l ? qm : q)*NN + o];
    }
    __syncthreads();
    // forward stage 1
    for (int i = t; i < nrow*264; i += TPB) {
        int l = i / 264, task = i - 264*l;
        s1_pair<1>(X[l], A[l], twN, T33, task);
    }
    __syncthreads();
    // forward stage 2 -> X
    for (int i = t; i < nrow*272; i += TPB) {
        int l = i / 272, task = i - 272*l;
        int o0, o1; float2 y0, y1;
        s2_pair<1>(A[l], T16, task, &o0, &y0, &o1, &y1);
        X[l][o0] = y0;
        if (o1 >= 0) X[l][o1] = y1;
    }
    __syncthreads();
    // Wiener apply: W(u=k, v=q) from precomputed field (coalesced float4 loads)
    const float4* Wrow = Wf + ((size_t)pr*NQ + q)*NN;
    int npair = (nrow == 2) ? NN : NQ;
    int lm = nrow - 1;
    for (int k = t; k < npair; k += TPB) {
        int km = (NN - k) % NN;
        float4 w = Wrow[k];
        float W0r = w.x, W0i = w.y, W1r = w.z, W1i = w.w;
        float2 Z  = X[0][k];
        float2 Zm = X[lm][km];
        float X0r = 0.5f*(Z.x + Zm.x), X0i = 0.5f*(Z.y - Zm.y);
        float X1r = 0.5f*(Z.y + Zm.y), X1i = 0.5f*(Zm.x - Z.x);
        float Y0r = X0r*W0r - X0i*W0i, Y0i = X0r*W0i + X0i*W0r;
        float Y1r = X1r*W1r - X1i*W1i, Y1i = X1r*W1i + X1i*W1r;
        X[0][k]   = make_float2(Y0r - Y1i, Y0i + Y1r);
        X[lm][km] = make_float2(Y0r + Y1i, Y1r - Y0i);
    }
    __syncthreads();
    // inverse stage 1
    for (int i = t; i < nrow*264; i += TPB) {
        int l = i / 264, task = i - 264*l;
        s1_pair<-1>(X[l], A[l], twN, T33, task);
    }
    __syncthreads();
    // inverse stage 2 -> X
    for (int i = t; i < nrow*272; i += TPB) {
        int l = i / 272, task = i - 272*l;
        int o0, o1; float2 y0, y1;
        s2_pair<-1>(A[l], T16, task, &o0, &y0, &o1, &y1);
        X[l][o0] = y0;
        if (o1 >= 0) X[l][o1] = y1;
    }
    __syncthreads();
    // store rows back (coalesced)
    for (int i = t; i < nrow*NN; i += TPB) {
        int l = i / NN, o = i - l*NN;
        pl[(size_t)(l ? qm : q)*NN + o] = X[l][o];
    }
}

// final inverse row-FFT fused with crop, 2 rows per 320-thread block
__global__ __launch_bounds__(TPB)
void fft_crop_k(const float2* __restrict__ in, float* __restrict__ out,
                const float2* __restrict__ twN) {
    __shared__ __align__(16) float2 X[2][NN];
    __shared__ __align__(16) float2 A[2][16*AST];
    __shared__ float2 T33[33];
    __shared__ float2 T16[16];
    int t = threadIdx.x;
    int bid = blockIdx.x;               // 12 * 256
    int q = bid >> 8;
    int rp0 = ((bid & 255) << 1) + PAD;
    int pair = q / 3, ch = q - 3*pair;
    int b0p = 2*pair;
    if (t < 33) T33[t] = twN[t*16];
    else if (t >= 64 && t < 80) T16[t-64] = twN[(t-64)*33];
    for (int i = t; i < 2*NN; i += TPB) {
        int l = i / NN, c = i - l*NN;
        X[l][c] = in[(size_t)q*NP + (size_t)(rp0 + l)*NN + c];
    }
    __syncthreads();
    for (int i = t; i < 2*264; i += TPB) {
        int l = i / 264, task = i - 264*l;
        s1_pair<-1>(X[l], A[l], twN, T33, task);
    }
    __syncthreads();
    for (int i = t; i < 2*272; i += TPB) {
        int l = i / 272, task = i - 272*l;
        int o0, o1; float2 y0, y1;
        s2_pair<-1>(A[l], T16, task, &o0, &y0, &o1, &y1);
        float* o0p = out + ((size_t)b0p*3 + ch) * IMGP + (size_t)(rp0 + l - PAD) * IMG;
        float* o1p = o0p + 3L*IMGP;
        if (o0 >= PAD && o0 < IMG + PAD) { o0p[o0 - PAD] = y0.x; o1p[o0 - PAD] = y0.y; }
        if (o1 >= PAD && o1 < IMG + PAD) { o0p[o1 - PAD] = y1.x; o1p[o1 - PAD] = y1.y; }
    }
}

extern "C" void kernel_launch(void* const* d_in, const int* in_sizes, int n_in,
                              void* d_out, int out_size, void* d_ws, size_t ws_size,
                              hipStream_t stream) {
    int i_img = -1, i_bk = -1, i_wcw = -1, i_ws = -1, i_4a = -1, i_4b = -1;
    for (int i = 0; i < n_in; ++i) {
        int s = in_sizes[i];
        if (s == 8*3*IMG*IMG)   i_img = i;
        else if (s == 8*KT)     i_bk = i;
        else if (s == NF*RKT)   i_wcw = i;
        else if (s == NF)       i_ws = i;
        else if (s == ND) { if (i_4a < 0) i_4a = i; else i_4b = i; }
    }
    if (i_img < 0) i_img = 0;
    if (i_bk  < 0) i_bk  = 1;
    if (i_wcw < 0) i_wcw = 3;
    if (i_ws  < 0) i_ws  = 4;
    if (i_4a  < 0) i_4a  = 5;
    if (i_4b  < 0) i_4b  = i_4a;
    const void* image      = d_in[i_img];
    const void* blurKernel = d_in[i_bk];
    const void* wcw        = d_in[i_wcw];
    const void* wscale     = d_in[i_ws];
    const float* c4a       = (const float*)d_in[i_4a];
    const float* c4b       = (const float*)d_in[i_4b];
    float* out = (float*)d_out;

    char* base = (char*)d_ws;
    int*    flags    = (int*)(base);
    float*  alpha_ws = (float*)(base + 64);
    float*  wgt_ws   = (float*)(base + 80);
    float2* twN      = (float2*)(base + 256);
    float*  wnorm    = (float*)(base + 4480);
    float*  psf_all  = (float*)(base + 6880);
    float*  A0       = (float*)(base + 16128);
    float*  A1       = (float*)(base + 33024);
    float*  Greg     = (float*)(base + 49920);      // NP*4 = 1115136
    float2* buf      = (float2*)(base + 1165056);   // 12*NP*8 = 26763264
    float*  borderV  = (float*)(base + 27928320);   // 24*BORD*4 = 3335808
    float2* Sv       = (float2*)(base + 31264128);  // 8*NN*KH*8 = 574464
    float4* Wf       = (float4*)(base + 31838592);  // 4*NQ*NN*16 = 8954880 -> end 40793472

    if (ws_size < 40793472) return;

    detect_k<<<1, 64, 0, stream>>>(image, in_sizes[i_img], blurKernel, in_sizes[i_bk],
                                   wcw, in_sizes[i_wcw], wscale, in_sizes[i_ws],
                                   c4a, c4b, flags, alpha_ws, wgt_ws);
    twinit_k<<<(NN+63)/64, 64, 0, stream>>>(twN);
    wnorm_k<<<1, 64, 0, stream>>>(wcw, wscale, flags, wnorm);
    prep_k<<<8, 64, 0, stream>>>(blurKernel, flags, psf_all, A0, A1);
    greg_k<<<(NP+255)/256, 256, 0, stream>>>(wnorm, twN, Greg);
    kv_k<<<(8*NN*KH+255)/256, 256, 0, stream>>>(psf_all, twN, Sv);
    wfilt_k<<<(4*NQ*NN+255)/256, 256, 0, stream>>>(Sv, Greg, twN, alpha_ws, wgt_ws, Wf);

    dim3 bgrid2(39, 24);
    border2_k<<<bgrid2, 256, 0, stream>>>(image, flags, psf_all, A0, A1, borderV);

    dim3 tblk(16, 16);
    dim3 tgrid12(561, 1, 12);
    dim3 rpgrid(NQ, 12);
    fftrow_k<<<12*264, TPB, 0, stream>>>(image, flags, borderV, twN, buf);
    transpose_ip_k<<<tgrid12, tblk, 0, stream>>>(buf);
    rowpipe_k<<<rpgrid, TPB, 0, stream>>>(buf, Wf, twN);
    transpose_ip_k<<<tgrid12, tblk, 0, stream>>>(buf);
    fft_crop_k<<<12*256, TPB, 0, stream>>>(buf, out, twN);
}

// Round 13
// 402.575 us; speedup vs baseline: 1.1428x; 1.1428x over previous
//
#include <hip/hip_runtime.h>
#include <hip/hip_bf16.h>

#define NN 528
#define NP (NN*NN)
#define IMG 512
#define IMGP (IMG*IMG)
#define PAD 8
#define KH 17
#define KT (KH*KH)
#define NF 24
#define RK 5
#define RKT (RK*RK)
#define ND 4
// per-channel border pixel counts
#define TOPB (17*NN)
#define ROWB (2*TOPB)
#define SIDEB (494*34)
#define BORD (ROWB + SIDEB)     // 34748
#define AST 34                  // padded A stride: even k2 is 16B-aligned for float4 reads
#define NQ 265                  // Hermitian slow-row count

static __device__ __forceinline__ float ldx(const void* p, long i, int bf) {
    if (bf) return __bfloat162float(((const __hip_bfloat16*)p)[i]);
    return ((const float*)p)[i];
}

// mirror-of-circular map: padded-domain offset m in [-16, 528) -> source index in [0,512)
static __device__ __forceinline__ int gmap(int m) {
    if (m < -8)  return 495 - m;   // -16..-9  -> 511..504
    if (m < 0)   return -m - 1;    // -8..-1   -> 7..0
    if (m < 512) return m;
    if (m < 520) return 1023 - m;  // 512..519 -> 511..504
    return 527 - m;                // 520..527 -> 7..0
}

// ---- 2-wide FFT stage bodies; compile-time sign S folds into FMA modifiers ----
// NOTE (R10/R12 lessons): 4-wide widening (dual recurrences, VGPR 120) and 5-wave
// blocks (TPB=320, SIMD imbalance on barriers) both regress. Keep 2-wide + 256 threads.
// stage 1: task = k2*8 + n1h; outputs A[2*n1h][k2], A[2*n1h+1][k2].
// Twiddle w_n = T33[k2]^n generated in-register (1 LDS read/task).
template<int S>
static __device__ __forceinline__ void s1_pair(const float2* __restrict__ X,
                                               float2* __restrict__ A,
                                               const float2* __restrict__ TW,
                                               const float2* __restrict__ T33,
                                               int task) {
    int k2 = task >> 3, n1h = task & 7, n1 = n1h << 1;
    const float4* Xv = (const float4*)X;
    float2 wst = T33[k2];
    float wr = 1.f, wi = 0.f;
    float a0r = 0.f, a0i = 0.f, a1r = 0.f, a1i = 0.f;
    for (int n2 = 0; n2 < 33; ++n2) {
        float4 xv = Xv[n1h + 8*n2];
        float ur = wr, ui = (S > 0) ? wi : -wi;
        a0r += xv.x*ur - xv.y*ui; a0i += xv.x*ui + xv.y*ur;
        a1r += xv.z*ur - xv.w*ui; a1i += xv.z*ui + xv.w*ur;
        float nwr = wr*wst.x - wi*wst.y;
        wi = wr*wst.y + wi*wst.x;
        wr = nwr;
    }
    float2 t0 = TW[n1*k2], t1 = TW[(n1+1)*k2];
    float t0r = t0.x, t0i = (S > 0) ? t0.y : -t0.y;
    float t1r = t1.x, t1i = (S > 0) ? t1.y : -t1.y;
    A[n1*AST + k2]     = make_float2(a0r*t0r - a0i*t0i, a0r*t0i + a0i*t0r);
    A[(n1+1)*AST + k2] = make_float2(a1r*t1r - a1i*t1i, a1r*t1i + a1i*t1r);
}

// stage 2: task = k1*17 + kp. kp<16 -> pair (2kp,2kp+1), kp=16 -> solo k2=32.
// Twiddle w_n = T16[k1]^n in-register (1 LDS read/task).
template<int S>
static __device__ __forceinline__ void s2_pair(const float2* __restrict__ A,
                                               const float2* __restrict__ T16,
                                               int task,
                                               int* o0, float2* y0, int* o1, float2* y1) {
    int k1 = task / 17, kp = task - 17*k1;
    float2 wst = T16[k1];
    float wr = 1.f, wi = 0.f;
    if (kp < 16) {
        int k2 = kp << 1;
        const float4* Av = (const float4*)A;
        float a0r = 0.f, a0i = 0.f, a1r = 0.f, a1i = 0.f;
        for (int n1 = 0; n1 < 16; ++n1) {
            float4 av = Av[(n1*AST + k2) >> 1];
            float ur = wr, ui = (S > 0) ? wi : -wi;
            a0r += av.x*ur - av.y*ui; a0i += av.x*ui + av.y*ur;
            a1r += av.z*ur - av.w*ui; a1i += av.z*ui + av.w*ur;
            float nwr = wr*wst.x - wi*wst.y;
            wi = wr*wst.y + wi*wst.x;
            wr = nwr;
        }
        *o0 = k1*33 + k2;     *y0 = make_float2(a0r, a0i);
        *o1 = k1*33 + k2 + 1; *y1 = make_float2(a1r, a1i);
    } else {
        float a0r = 0.f, a0i = 0.f;
        for (int n1 = 0; n1 < 16; ++n1) {
            float2 av = A[n1*AST + 32];
            float ur = wr, ui = (S > 0) ? wi : -wi;
            a0r += av.x*ur - av.y*ui; a0i += av.x*ui + av.y*ur;
            float nwr = wr*wst.x - wi*wst.y;
            wi = wr*wst.y + wi*wst.x;
            wr = nwr;
        }
        *o0 = k1*33 + 32; *y0 = make_float2(a0r, a0i);
        *o1 = -1;
    }
}

__global__ void detect_k(const void* pimg, int nimg, const void* pbk, int nbk,
                         const void* pwcw, int nwcw, const void* pws, int nws,
                         const float* c4a, const float* c4b,
                         int* __restrict__ flags,
                         float* __restrict__ alpha_ws, float* __restrict__ wgt_ws) {
    int t = threadIdx.x;
    const void* ps[4] = {pimg, pbk, pwcw, pws};
    int ns[4] = {nimg, nbk, nwcw, nws};
    if (t < 4) {
        const unsigned short* q = (const unsigned short*)ps[t];
        int n = ns[t];
        int K = n < 512 ? n : 512;
        int cnt = 0, pass = 0;
        for (int i = 0; i < K; i += 2) {
            int e = (q[i] >> 7) & 0xFF;
            pass += (e >= 100 && e <= 140);
            cnt++;
        }
        flags[t] = (pass * 10 >= cnt * 8) ? 1 : 0;
    }
    if (t == 7) {
        const float* A = (c4a[0] < 0.f) ? c4a : c4b;
        const float* W = (c4a[0] < 0.f) ? c4b : c4a;
        for (int i = 0; i < ND; ++i) { alpha_ws[i] = A[i]; wgt_ws[i] = W[i]; }
    }
}

__global__ void twinit_k(float2* __restrict__ twN) {
    int i = blockIdx.x * blockDim.x + threadIdx.x;
    if (i < NN) {
        double th = -6.283185307179586476925287 * (double)i / (double)NN;
        twN[i] = make_float2((float)cos(th), (float)sin(th));
    }
}

__global__ void wnorm_k(const void* __restrict__ wcw, const void* __restrict__ wscale,
                        const int* __restrict__ flags, float* __restrict__ wout) {
    int f = threadIdx.x;
    if (f >= NF) return;
    int bfw = flags[2], bfs = flags[3];
    float v[RKT];
    float mean = 0.f;
    for (int i = 0; i < RKT; ++i) { v[i] = ldx(wcw, f*RKT+i, bfw); mean += v[i]; }
    mean *= (1.f/(float)RKT);
    float ss = 0.f;
    for (int i = 0; i < RKT; ++i) { v[i] -= mean; ss += v[i]*v[i]; }
    float sc = ldx(wscale, f, bfs) / sqrtf(ss);
    for (int i = 0; i < RKT; ++i) wout[f*RKT+i] = v[i]*sc;
}

__global__ void prep_k(const void* __restrict__ blurKernel, const int* __restrict__ flags,
                       float* __restrict__ psf_all, float* __restrict__ A0_all,
                       float* __restrict__ A1_all) {
    int b = blockIdx.x, t = threadIdx.x;
    int bf = flags[1];
    __shared__ float psf[KT];
    __shared__ float q0[KH], q1[KH], ac0[KH], ac1[KH];
    for (int i = t; i < KT; i += 64) {
        float v = ldx(blurKernel, b*KT + i, bf);
        psf[i] = v;
        psf_all[b*KT + i] = v;
    }
    __syncthreads();
    if (t < KH) {
        float s0 = 0.f, s1 = 0.f;
        for (int k = 0; k < KH; ++k) { s0 += psf[t*KH + k]; s1 += psf[k*KH + t]; }
        q0[t] = s0; q1[t] = s1;
    }
    __syncthreads();
    if (t < KH) {
        float a0 = 0.f, a1 = 0.f;
        for (int m = 0; m + t < KH; ++m) { a0 += q0[m]*q0[m+t]; a1 += q1[m]*q1[m+t]; }
        ac0[t] = a0; ac1[t] = a1;
    }
    __syncthreads();
    for (int r = t; r < NN; r += 64) {
        int lag = min(r, (NN-1) - r);
        float b0 = (lag <= KH-1) ? ac0[lag]/ac0[0] : 0.f;
        float b1 = (lag <= KH-1) ? ac1[lag]/ac1[0] : 0.f;
        A0_all[b*NN + r] = 1.f - b0;
        A1_all[b*NN + r] = 1.f - b1;
    }
}

// Greg in transposed frequency layout: p = kc*NN + kr (verified R6)
__global__ void greg_k(const float* __restrict__ w, const float2* __restrict__ twN,
                       float* __restrict__ Greg) {
    int p = blockIdx.x * blockDim.x + threadIdx.x;
    if (p >= NP) return;
    int u = p % NN, v = p / NN;
    float2 rp[RK], cp[RK];
    for (int j = 0; j < RK; ++j) {
        int m = (u * (j - RK/2)) % NN; if (m < 0) m += NN;
        rp[j] = twN[m];
    }
    for (int k = 0; k < RK; ++k) {
        int m = (v * (k - RK/2)) % NN; if (m < 0) m += NN;
        cp[k] = twN[m];
    }
    float pr[RKT], pi[RKT];
    for (int j = 0; j < RK; ++j)
        for (int k = 0; k < RK; ++k) {
            pr[j*RK+k] = rp[j].x*cp[k].x - rp[j].y*cp[k].y;
            pi[j*RK+k] = rp[j].x*cp[k].y + rp[j].y*cp[k].x;
        }
    float acc = 0.f;
    for (int f = 0; f < NF; ++f) {
        float gr = 0.f, gi = 0.f;
        for (int i = 0; i < RKT; ++i) {
            float wv = w[f*RKT + i];
            gr += wv * pr[i];
            gi += wv * pi[i];
        }
        acc += gr*gr + gi*gi;
    }
    Greg[p] = acc;
}

// LDS-tiled border edgetaper (R1-verified).
__global__ __launch_bounds__(256)
void border2_k(const void* __restrict__ image, const int* __restrict__ flags,
               const float* __restrict__ psf_all,
               const float* __restrict__ A0_all, const float* __restrict__ A1_all,
               float* __restrict__ borderV) {
    __shared__ float4 S4[1440];           // 23040 B; tb uses 20x288 floats, side 42x84
    float* S = (float*)S4;
    int bp = blockIdx.y;                  // plane 0..23
    int b = bp / 3;
    long ofs = (long)bp * IMGP;
    int bf = flags[0];
    int t = threadIdx.x;
    const float* pw = psf_all + b*KT;
    int bx = blockIdx.x;

    if (bx < 20) {
        int q = bx >> 1, h = bx & 1;
        int r0;
        if (q < 4) r0 = 4*q;
        else if (q == 4) r0 = 13;
        else if (q < 9) r0 = 511 + 4*(q-5);
        else r0 = 524;
        int X0 = h * 264;
        for (int idx = t; idx < 20*288; idx += 256) {
            int i = idx / 288, xi = idx - i*288;
            int x = X0 + xi;
            float v = 0.f;
            if (x < 544) {
                int sr = gmap(r0 - 16 + i);
                int sc = gmap(x - 16);
                v = ldx(image, ofs + (long)sr*IMG + sc, bf);
            }
            S[idx] = v;
        }
        __syncthreads();
        for (int g = t; g < 264; g += 256) {
            int rx = g / 66, cl = g - rx*66;
            int c0 = X0 + 4*cl;
            int x0 = 4*cl;
            float acc0 = 0.f, acc1 = 0.f, acc2 = 0.f, acc3 = 0.f;
            for (int j = 0; j < KH; ++j) {
                const float4* SjV = (const float4*)(S + (16 + rx - j)*288 + x0);
                float xv[20];
                #pragma unroll
                for (int qv = 0; qv < 5; ++qv) {
                    float4 tv = SjV[qv];
                    xv[4*qv+0] = tv.x; xv[4*qv+1] = tv.y;
                    xv[4*qv+2] = tv.z; xv[4*qv+3] = tv.w;
                }
                const float* wj = pw + j*KH;
                #pragma unroll
                for (int qq = 0; qq < 20; ++qq) {
                    {int k = 0 + 16 - qq; if (k >= 0 && k < KH) acc0 += wj[k]*xv[qq];}
                    {int k = 1 + 16 - qq; if (k >= 0 && k < KH) acc1 += wj[k]*xv[qq];}
                    {int k = 2 + 16 - qq; if (k >= 0 && k < KH) acc2 += wj[k]*xv[qq];}
                    {int k = 3 + 16 - qq; if (k >= 0 && k < KH) acc3 += wj[k]*xv[qq];}
                }
            }
            int r = r0 + rx;
            float a0v = A0_all[b*NN + r];
            int ibase = (r < 17) ? r*NN : TOPB + (r-511)*NN;
            float accs[4] = {acc0, acc1, acc2, acc3};
            #pragma unroll
            for (int d = 0; d < 4; ++d) {
                int c = c0 + d;
                float xo = S[(8 + rx)*288 + (x0 + 8 + d)];
                float al = a0v * A1_all[b*NN + c];
                borderV[(size_t)bp*BORD + ibase + c] = al*xo + (1.f - al)*accs[d];
            }
        }
    } else {
        int chunk = bx - 20;
        int r0 = 17 + 26*chunk;
        for (int idx = t; idx < 42*84; idx += 256) {
            int i = idx / 84, x = idx - i*84;
            float v = 0.f;
            int m = -1000;
            if (x < 33) m = x - 16;
            else if (x >= 48 && x < 81) m = x - 48 + 495;
            if (m != -1000) {
                int sr = gmap(r0 - 16 + i);
                int sc = gmap(m);
                v = ldx(image, ofs + (long)sr*IMG + sc, bf);
            }
            S[idx] = v;
        }
        __syncthreads();
        int g = t;
        if (g < 208) {
            int ry = g >> 3, s = g & 7;
            int c0 = (s < 4) ? 4*s : 511 + 4*(s-4);
            int sz = ((s & 3) == 3) ? 5 : 4;
            int x0 = (s < 4) ? 4*s : 48 + 4*(s-4);
            float acc0=0.f, acc1=0.f, acc2=0.f, acc3=0.f, acc4=0.f;
            for (int j = 0; j < KH; ++j) {
                const float4* SjV = (const float4*)(S + (16 + ry - j)*84 + x0);
                float xv[24];
                #pragma unroll
                for (int qv = 0; qv < 6; ++qv) {
                    float4 tv = SjV[qv];
                    xv[4*qv+0] = tv.x; xv[4*qv+1] = tv.y;
                    xv[4*qv+2] = tv.z; xv[4*qv+3] = tv.w;
                }
                const float* wj = pw + j*KH;
                #pragma unroll
                for (int qq = 0; qq < 21; ++qq) {
                    {int k = 0 + 16 - qq; if (k >= 0 && k < KH) acc0 += wj[k]*xv[qq];}
                    {int k = 1 + 16 - qq; if (k >= 0 && k < KH) acc1 += wj[k]*xv[qq];}
                    {int k = 2 + 16 - qq; if (k >= 0 && k < KH) acc2 += wj[k]*xv[qq];}
                    {int k = 3 + 16 - qq; if (k >= 0 && k < KH) acc3 += wj[k]*xv[qq];}
                    {int k = 4 + 16 - qq; if (k >= 0 && k < KH) acc4 += wj[k]*xv[qq];}
                }
            }
            int r = r0 + ry;
            float a0v = A0_all[b*NN + r];
            int cc0 = (s < 4) ? c0 : c0 - 494;
            size_t ib = (size_t)bp*BORD + ROWB + (size_t)(r-17)*34 + cc0;
            float accs[5] = {acc0, acc1, acc2, acc3, acc4};
            #pragma unroll
            for (int d = 0; d < 5; ++d) {
                if (d < sz) {
                    int c = c0 + d;
                    float xo = S[(8 + ry)*84 + (x0 + 8 + d)];
                    float al = a0v * A1_all[b*NN + c];
                    borderV[ib + d] = al*xo + (1.f - al)*accs[d];
                }
            }
        }
    }
}

// column-sum factor S(b, v, j) = sum_k psf[b][j][k] * tw[v*(k-8)]  (u-independent part of K)
__global__ void kv_k(const float* __restrict__ psf_all, const float2* __restrict__ twN,
                     float2* __restrict__ Sv) {
    int idx = blockIdx.x * blockDim.x + threadIdx.x;
    if (idx >= 8*NN*KH) return;
    int j = idx % KH;
    int rest = idx / KH;
    int v = rest % NN, b = rest / NN;
    int m = (520 * v) % NN;   // (-8v) mod 528
    float sr = 0.f, si = 0.f;
    const float* ps = psf_all + b*KT + j*KH;
    for (int k = 0; k < KH; ++k) {
        float2 cp = twN[m];
        m += v; if (m >= NN) m -= NN;
        sr += ps[k] * cp.x;
        si += ps[k] * cp.y;
    }
    Sv[idx] = make_float2(sr, si);
}

// Precomputed Wiener filter field: Wf[((pair*NQ + q)*NN) + k] = (W0r, W0i, W1r, W1i).
__global__ __launch_bounds__(256)
void wfilt_k(const float2* __restrict__ Sv, const float* __restrict__ Greg,
             const float2* __restrict__ twN,
             const float* __restrict__ alpha4, const float* __restrict__ wgt4,
             float4* __restrict__ Wf) {
    int idx = blockIdx.x * blockDim.x + threadIdx.x;
    if (idx >= 4*NQ*NN) return;
    int k = idx % NN;
    int rest = idx / NN;
    int q = rest % NQ, pr = rest / NQ;
    int b0p = 2*pr;
    const float2* S0 = Sv + ((size_t)b0p*NN + q)*KH;
    const float2* S1 = Sv + ((size_t)(b0p+1)*NN + q)*KH;
    int mu0 = (520 * k) % NN;
    float2 rp = twN[mu0];
    float2 rst = twN[k];
    float K0r = 0.f, K0i = 0.f, K1r = 0.f, K1i = 0.f;
    for (int j = 0; j < KH; ++j) {
        float2 s0 = S0[j], s1 = S1[j];
        K0r += rp.x*s0.x - rp.y*s0.y;  K0i += rp.x*s0.y + rp.y*s0.x;
        K1r += rp.x*s1.x - rp.y*s1.y;  K1i += rp.x*s1.y + rp.y*s1.x;
        float nrp = rp.x*rst.x - rp.y*rst.y;
        rp.y = rp.x*rst.y + rp.y*rst.x;
        rp.x = nrp;
    }
    float gg = Greg[(size_t)q*NN + k];
    float K20 = K0r*K0r + K0i*K0i;
    float K21 = K1r*K1r + K1i*K1i;
    float s0a = 0.f, s1a = 0.f;
    #pragma unroll
    for (int d = 0; d < ND; ++d) {
        float a = __expf(alpha4[d]);
        float wd = wgt4[d];
        s0a += wd * __builtin_amdgcn_rcpf(fmaxf(K20 + a*gg, 1e-30f));
        s1a += wd * __builtin_amdgcn_rcpf(fmaxf(K21 + a*gg, 1e-30f));
    }
    s0a *= (1.f/(float)NP);
    s1a *= (1.f/(float)NP);
    Wf[idx] = make_float4(K0r*s0a, -K0i*s0a, K1r*s1a, -K1i*s1a);
}

// fused pad + forward row FFT, 2 rows per 256-thread block, all 12 packed planes
__global__ __launch_bounds__(256)
void fftrow_k(const void* __restrict__ image, const int* __restrict__ flags,
              const float* __restrict__ borderV, const float2* __restrict__ twN,
              float2* __restrict__ buf) {
    __shared__ __align__(16) float2 X[2][NN];
    __shared__ __align__(16) float2 A[2][16*AST];
    __shared__ float2 TW[NN];
    __shared__ float2 T33[33];
    __shared__ float2 T16[16];
    int t = threadIdx.x;
    int bid = blockIdx.x;               // 12 * 264
    int q = bid / 264;
    int r0 = (bid - q*264) << 1;
    int pair = q / 3, ch = q - 3*pair;
    int b0p = 2*pair;
    int bf = flags[0];
    for (int i = t; i < NN; i += 256) TW[i] = twN[i];
    if (t < 33) T33[t] = twN[t*16];
    else if (t >= 64 && t < 80) T16[t-64] = twN[(t-64)*33];
    for (int i = t; i < 2*NN; i += 256) {
        int l = i / NN, c = i - l*NN;
        int r = r0 + l;
        float x0, x1;
        bool isb = (r < 17) | (r >= 511) | (c < 17) | (c >= 511);
        if (isb) {
            int i2;
            if (r < 17) i2 = r*NN + c;
            else if (r >= 511) i2 = TOPB + (r-511)*NN + c;
            else { int cc = (c < 17) ? c : c - 494; i2 = ROWB + (r-17)*34 + cc; }
            x0 = borderV[(size_t)(b0p*3 + ch)*BORD + i2];
            x1 = borderV[(size_t)((b0p+1)*3 + ch)*BORD + i2];
        } else {
            long ofs0 = ((long)b0p*3 + ch) * IMGP + (long)(r - PAD)*IMG + (c - PAD);
            x0 = ldx(image, ofs0, bf);
            x1 = ldx(image, ofs0 + 3L*IMGP, bf);
        }
        X[l][c] = make_float2(x0, x1);
    }
    __syncthreads();
    for (int i = t; i < 2*264; i += 256) {
        int l = i / 264, task = i - 264*l;
        s1_pair<1>(X[l], A[l], TW, T33, task);
    }
    __syncthreads();
    for (int i = t; i < 2*272; i += 256) {
        int l = i / 272, task = i - 272*l;
        int o0, o1; float2 y0, y1;
        s2_pair<1>(A[l], T16, task, &o0, &y0, &o1, &y1);
        float2* dst = buf + (size_t)q*NP + (size_t)(r0 + l)*NN;
        dst[o0] = y0;
        if (o1 >= 0) dst[o1] = y1;
    }
}

// in-place square transpose: tile-pair swap, 561 upper-tri tiles per plane (z = 12 planes)
__global__ void transpose_ip_k(float2* __restrict__ buf) {
    int tnum = blockIdx.x;
    int ti = 0, rem = tnum;
    while (rem >= 33 - ti) { rem -= 33 - ti; ti++; }
    int tj = ti + rem;
    float2* pl = buf + (size_t)blockIdx.z * NP;
    __shared__ float2 ta[16][17], tb[16][17];
    int tx = threadIdx.x, ty = threadIdx.y;
    int ra = ti*16 + ty, ca = tj*16 + tx;
    int rb = tj*16 + ty, cb = ti*16 + tx;
    ta[ty][tx] = pl[(size_t)ra*NN + ca];
    tb[ty][tx] = pl[(size_t)rb*NN + cb];
    __syncthreads();
    pl[(size_t)ra*NN + ca] = tb[tx][ty];
    pl[(size_t)rb*NN + cb] = ta[tx][ty];
}

// Fused cols-fwd + Wiener + cols-inv on TRANSPOSED buffer; W loaded from precomputed field.
__global__ __launch_bounds__(256)
void rowpipe_k(float2* __restrict__ buf, const float4* __restrict__ Wf,
               const float2* __restrict__ twN) {
    __shared__ __align__(16) float2 X[2][NN];
    __shared__ __align__(16) float2 A[2][16*AST];
    __shared__ float2 TW[NN];
    __shared__ float2 T33[33];
    __shared__ float2 T16[16];
    int t = threadIdx.x;
    int q = blockIdx.x;                 // 0..264
    int plane = blockIdx.y;             // 0..11
    int pr = plane / 3;
    int qm = (NN - q) % NN;
    int nrow = (qm == q) ? 1 : 2;
    float2* pl = buf + (size_t)plane * NP;
    for (int i = t; i < NN; i += 256) TW[i] = twN[i];
    if (t < 33) T33[t] = twN[t*16];
    else if (t >= 64 && t < 80) T16[t-64] = twN[(t-64)*33];
    // load rows (coalesced)
    for (int i = t; i < nrow*NN; i += 256) {
        int l = i / NN, o = i - l*NN;
        X[l][o] = pl[(size_t)(l ? qm : q)*NN + o];
    }
    __syncthreads();
    // forward stage 1
    for (int i = t; i < nrow*264; i += 256) {
        int l = i / 264, task = i - 264*l;
        s1_pair<1>(X[l], A[l], TW, T33, task);
    }
    __syncthreads();
    // forward stage 2 -> X
    for (int i = t; i < nrow*272; i += 256) {
        int l = i / 272, task = i - 272*l;
        int o0, o1; float2 y0, y1;
        s2_pair<1>(A[l], T16, task, &o0, &y0, &o1, &y1);
        X[l][o0] = y0;
        if (o1 >= 0) X[l][o1] = y1;
    }
    __syncthreads();
    // Wiener apply: W(u=k, v=q) from precomputed field (coalesced float4 loads)
    const float4* Wrow = Wf + ((size_t)pr*NQ + q)*NN;
    int npair = (nrow == 2) ? NN : NQ;
    int lm = nrow - 1;
    for (int k = t; k < npair; k += 256) {
        int km = (NN - k) % NN;
        float4 w = Wrow[k];
        float W0r = w.x, W0i = w.y, W1r = w.z, W1i = w.w;
        float2 Z  = X[0][k];
        float2 Zm = X[lm][km];
        float X0r = 0.5f*(Z.x + Zm.x), X0i = 0.5f*(Z.y - Zm.y);
        float X1r = 0.5f*(Z.y + Zm.y), X1i = 0.5f*(Zm.x - Z.x);
        float Y0r = X0r*W0r - X0i*W0i, Y0i = X0r*W0i + X0i*W0r;
        float Y1r = X1r*W1r - X1i*W1i, Y1i = X1r*W1i + X1i*W1r;
        X[0][k]   = make_float2(Y0r - Y1i, Y0i + Y1r);
        X[lm][km] = make_float2(Y0r + Y1i, Y1r - Y0i);
    }
    __syncthreads();
    // inverse stage 1
    for (int i = t; i < nrow*264; i += 256) {
        int l = i / 264, task = i - 264*l;
        s1_pair<-1>(X[l], A[l], TW, T33, task);
    }
    __syncthreads();
    // inverse stage 2 -> X
    for (int i = t; i < nrow*272; i += 256) {
        int l = i / 272, task = i - 272*l;
        int o0, o1; float2 y0, y1;
        s2_pair<-1>(A[l], T16, task, &o0, &y0, &o1, &y1);
        X[l][o0] = y0;
        if (o1 >= 0) X[l][o1] = y1;
    }
    __syncthreads();
    // store rows back (coalesced)
    for (int i = t; i < nrow*NN; i += 256) {
        int l = i / NN, o = i - l*NN;
        pl[(size_t)(l ? qm : q)*NN + o] = X[l][o];
    }
}

// final inverse row-FFT fused with crop, 2 rows per 256-thread block
__global__ __launch_bounds__(256)
void fft_crop_k(const float2* __restrict__ in, float* __restrict__ out,
                const float2* __restrict__ twN) {
    __shared__ __align__(16) float2 X[2][NN];
    __shared__ __align__(16) float2 A[2][16*AST];
    __shared__ float2 TW[NN];
    __shared__ float2 T33[33];
    __shared__ float2 T16[16];
    int t = threadIdx.x;
    int bid = blockIdx.x;               // 12 * 256
    int q = bid >> 8;
    int rp0 = ((bid & 255) << 1) + PAD;
    int pair = q / 3, ch = q - 3*pair;
    int b0p = 2*pair;
    for (int i = t; i < NN; i += 256) TW[i] = twN[i];
    if (t < 33) T33[t] = twN[t*16];
    else if (t >= 64 && t < 80) T16[t-64] = twN[(t-64)*33];
    for (int i = t; i < 2*NN; i += 256) {
        int l = i / NN, c = i - l*NN;
        X[l][c] = in[(size_t)q*NP + (size_t)(rp0 + l)*NN + c];
    }
    __syncthreads();
    for (int i = t; i < 2*264; i += 256) {
        int l = i / 264, task = i - 264*l;
        s1_pair<-1>(X[l], A[l], TW, T33, task);
    }
    __syncthreads();
    for (int i = t; i < 2*272; i += 256) {
        int l = i / 272, task = i - 272*l;
        int o0, o1; float2 y0, y1;
        s2_pair<-1>(A[l], T16, task, &o0, &y0, &o1, &y1);
        float* o0p = out + ((size_t)b0p*3 + ch) * IMGP + (size_t)(rp0 + l - PAD) * IMG;
        float* o1p = o0p + 3L*IMGP;
        if (o0 >= PAD && o0 < IMG + PAD) { o0p[o0 - PAD] = y0.x; o1p[o0 - PAD] = y0.y; }
        if (o1 >= PAD && o1 < IMG + PAD) { o0p[o1 - PAD] = y1.x; o1p[o1 - PAD] = y1.y; }
    }
}

extern "C" void kernel_launch(void* const* d_in, const int* in_sizes, int n_in,
                              void* d_out, int out_size, void* d_ws, size_t ws_size,
                              hipStream_t stream) {
    int i_img = -1, i_bk = -1, i_wcw = -1, i_ws = -1, i_4a = -1, i_4b = -1;
    for (int i = 0; i < n_in; ++i) {
        int s = in_sizes[i];
        if (s == 8*3*IMG*IMG)   i_img = i;
        else if (s == 8*KT)     i_bk = i;
        else if (s == NF*RKT)   i_wcw = i;
        else if (s == NF)       i_ws = i;
        else if (s == ND) { if (i_4a < 0) i_4a = i; else i_4b = i; }
    }
    if (i_img < 0) i_img = 0;
    if (i_bk  < 0) i_bk  = 1;
    if (i_wcw < 0) i_wcw = 3;
    if (i_ws  < 0) i_ws  = 4;
    if (i_4a  < 0) i_4a  = 5;
    if (i_4b  < 0) i_4b  = i_4a;
    const void* image      = d_in[i_img];
    const void* blurKernel = d_in[i_bk];
    const void* wcw        = d_in[i_wcw];
    const void* wscale     = d_in[i_ws];
    const float* c4a       = (const float*)d_in[i_4a];
    const float* c4b       = (const float*)d_in[i_4b];
    float* out = (float*)d_out;

    char* base = (char*)d_ws;
    int*    flags    = (int*)(base);
    float*  alpha_ws = (float*)(base + 64);
    float*  wgt_ws   = (float*)(base + 80);
    float2* twN      = (float2*)(base + 256);
    float*  wnorm    = (float*)(base + 4480);
    float*  psf_all  = (float*)(base + 6880);
    float*  A0       = (float*)(base + 16128);
    float*  A1       = (float*)(base + 33024);
    float*  Greg     = (float*)(base + 49920);      // NP*4 = 1115136
    float2* buf      = (float2*)(base + 1165056);   // 12*NP*8 = 26763264
    float*  borderV  = (float*)(base + 27928320);   // 24*BORD*4 = 3335808
    float2* Sv       = (float2*)(base + 31264128);  // 8*NN*KH*8 = 574464
    float4* Wf       = (float4*)(base + 31838592);  // 4*NQ*NN*16 = 8954880 -> end 40793472

    if (ws_size < 40793472) return;

    detect_k<<<1, 64, 0, stream>>>(image, in_sizes[i_img], blurKernel, in_sizes[i_bk],
                                   wcw, in_sizes[i_wcw], wscale, in_sizes[i_ws],
                                   c4a, c4b, flags, alpha_ws, wgt_ws);
    twinit_k<<<(NN+63)/64, 64, 0, stream>>>(twN);
    wnorm_k<<<1, 64, 0, stream>>>(wcw, wscale, flags, wnorm);
    prep_k<<<8, 64, 0, stream>>>(blurKernel, flags, psf_all, A0, A1);
    greg_k<<<(NP+255)/256, 256, 0, stream>>>(wnorm, twN, Greg);
    kv_k<<<(8*NN*KH+255)/256, 256, 0, stream>>>(psf_all, twN, Sv);
    wfilt_k<<<(4*NQ*NN+255)/256, 256, 0, stream>>>(Sv, Greg, twN, alpha_ws, wgt_ws, Wf);

    dim3 bgrid2(39, 24);
    border2_k<<<bgrid2, 256, 0, stream>>>(image, flags, psf_all, A0, A1, borderV);

    dim3 tblk(16, 16);
    dim3 tgrid12(561, 1, 12);
    dim3 rpgrid(NQ, 12);
    fftrow_k<<<12*264, 256, 0, stream>>>(image, flags, borderV, twN, buf);
    transpose_ip_k<<<tgrid12, tblk, 0, stream>>>(buf);
    rowpipe_k<<<rpgrid, 256, 0, stream>>>(buf, Wf, twN);
    transpose_ip_k<<<tgrid12, tblk, 0, stream>>>(buf);
    fft_crop_k<<<12*256, 256, 0, stream>>>(buf, out, twN);
}